// Round 2
// baseline (286.141 us; speedup 1.0000x reference)
//
#include <hip/hip_runtime.h>

// Problem constants (fixed by setup_inputs)
constexpr int PEP = 15;   // peptide length
constexpr int D   = 64;   // feature dim (= wave size)
constexpr int L   = 34;   // mhc length (contraction dim of stage 1)
constexpr int OC  = 128;  // output channels
constexpr int KS  = 9;    // kernel size
constexpr int TO  = 7;    // (15-9)/1+1
constexpr int LP  = 36;   // padded W row (float4-aligned)
constexpr int SOP = 900;  // so plane stride: 900%32=4 -> partial planes hit different banks

// Pre-pass: pad W rows 34 -> 36 floats so every row is 16B-aligned.
__global__ void wpad_kernel(const float* __restrict__ W, float* __restrict__ wp) {
    int i = blockIdx.x * 256 + threadIdx.x;          // over OC*KS*LP
    if (i >= OC * KS * LP) return;
    int l  = i % LP;
    int ok = i / LP;
    wp[i] = (l < L) ? W[ok * L + l] : 0.0f;
}

// Main kernel: one block per batch element n. 4 waves; lane = d.
// Each wave handles 32 output channels. Weight rows are wave-uniform
// (scalar-load candidates); mhc/pep columns live in registers.
template <bool PAD>
__global__ __launch_bounds__(256, 4) void iconv_kernel(
    const float* __restrict__ pep,
    const float* __restrict__ mhc,
    const float* __restrict__ wsrc,   // padded (PAD) or original layout
    const float* __restrict__ bias,
    float* __restrict__ out)
{
    __shared__ float so[4 * SOP];     // [partial-plane][o*TO+t]

    const int n    = blockIdx.x;
    const int tid  = threadIdx.x;
    const int lane = tid & 63;                      // = d
    const int w    = __builtin_amdgcn_readfirstlane(tid >> 6);

    // mhc column d: m[l] = mhc[n][l][lane]   (coalesced, stride D)
    float m[L];
    {
        const float* mp = mhc + (size_t)n * L * D + lane;
        #pragma unroll
        for (int l = 0; l < L; ++l) m[l] = mp[l * D];
    }
    // pep column d: p[j] = pep[n][j][lane]
    float p[PEP];
    {
        const float* pp = pep + (size_t)n * PEP * D + lane;
        #pragma unroll
        for (int j = 0; j < PEP; ++j) p[j] = pp[j * D];
    }

    for (int oo = 0; oo < OC / 4; ++oo) {
        const int o = w * (OC / 4) + oo;            // wave-uniform

        float acc[TO];
        #pragma unroll
        for (int t = 0; t < TO; ++t) acc[t] = 0.0f;

        #pragma unroll
        for (int k = 0; k < KS; ++k) {
            // Load the wave-uniform weight row (scalar-load candidate).
            float wr[LP];
            if constexpr (PAD) {
                const float4* wrow = reinterpret_cast<const float4*>(wsrc + (size_t)o * KS * LP);
                #pragma unroll
                for (int q = 0; q < LP / 4; ++q) {
                    float4 v = wrow[k * (LP / 4) + q];
                    wr[q * 4 + 0] = v.x; wr[q * 4 + 1] = v.y;
                    wr[q * 4 + 2] = v.z; wr[q * 4 + 3] = v.w;
                }
            } else {
                const float2* wrow = reinterpret_cast<const float2*>(wsrc + (size_t)o * KS * L);
                #pragma unroll
                for (int q = 0; q < L / 2; ++q) {
                    float2 v = wrow[k * (L / 2) + q];
                    wr[q * 2 + 0] = v.x; wr[q * 2 + 1] = v.y;
                }
                #pragma unroll
                for (int q = L; q < LP; ++q) wr[q] = 0.0f;
            }

            // 4-way split of the L=34 dot product: dependent chain 34 -> 9.
            float k0 = 0.0f, k1 = 0.0f, k2 = 0.0f, k3 = 0.0f;
            #pragma unroll
            for (int l = 0; l < 32; l += 4) {
                k0 = fmaf(m[l + 0], wr[l + 0], k0);
                k1 = fmaf(m[l + 1], wr[l + 1], k1);
                k2 = fmaf(m[l + 2], wr[l + 2], k2);
                k3 = fmaf(m[l + 3], wr[l + 3], k3);
            }
            k0 = fmaf(m[32], wr[32], k0);
            k1 = fmaf(m[33], wr[33], k1);
            float kk = fmaxf((k0 + k2) + (k1 + k3), 0.0f);   // ReLU

            #pragma unroll
            for (int t = 0; t < TO; ++t) acc[t] = fmaf(p[t + k], kk, acc[t]);
        }

        // Partial butterfly over strides 1,2,4,8 (DPP-friendly): every
        // 16-lane group ends holding its group sum. Lanes {0,16,32,48}
        // stash 4 partials; the epilogue folds them.
        #pragma unroll
        for (int t = 0; t < TO; ++t) {
            float a = acc[t];
            a += __shfl_xor(a, 1, 64);
            a += __shfl_xor(a, 2, 64);
            a += __shfl_xor(a, 4, 64);
            a += __shfl_xor(a, 8, 64);
            if ((lane & 15) == 0) so[(lane >> 4) * SOP + o * TO + t] = a;
        }
    }

    __syncthreads();

    // Coalesced epilogue: out[n][o][t] = sum of 4 partials + bias[o]
    float* on = out + (size_t)n * OC * TO;
    for (int i = tid; i < OC * TO; i += 256) {
        int o = i / TO;
        float v = (so[i] + so[SOP + i]) + (so[2 * SOP + i] + so[3 * SOP + i]);
        on[i] = v + bias[o];
    }
}

extern "C" void kernel_launch(void* const* d_in, const int* in_sizes, int n_in,
                              void* d_out, int out_size, void* d_ws, size_t ws_size,
                              hipStream_t stream) {
    const float* pep  = (const float*)d_in[0];
    const float* mhc  = (const float*)d_in[1];
    const float* W    = (const float*)d_in[2];
    const float* bias = (const float*)d_in[3];
    float* out        = (float*)d_out;

    const int bs = in_sizes[0] / (PEP * D);   // 2048

    const size_t pad_bytes = (size_t)OC * KS * LP * sizeof(float);
    const bool use_pad = (d_ws != nullptr) && (ws_size >= pad_bytes);

    if (use_pad) {
        float* wp = (float*)d_ws;
        wpad_kernel<<<(OC * KS * LP + 255) / 256, 256, 0, stream>>>(W, wp);
        iconv_kernel<true><<<bs, 256, 0, stream>>>(pep, mhc, wp, bias, out);
    } else {
        iconv_kernel<false><<<bs, 256, 0, stream>>>(pep, mhc, W, bias, out);
    }
}

// Round 4
// 280.456 us; speedup vs baseline: 1.0203x; 1.0203x over previous
//
#include <hip/hip_runtime.h>

typedef __attribute__((ext_vector_type(8))) short bf16x8;
typedef __attribute__((ext_vector_type(4))) float f32x4;
typedef unsigned short ushort_t;
typedef unsigned int uint_t;

constexpr int PEP = 15;   // peptide length
constexpr int D   = 64;   // feature dim
constexpr int L   = 34;   // mhc length (stage-1 contraction)
constexpr int OC  = 128;  // output channels
constexpr int KS  = 9;    // kernel size
constexpr int TO  = 7;    // output positions
constexpr int OK  = OC * KS;      // 1152 rows of stage-1
constexpr int MTG = OK / 16;      // 72 global M-tiles
constexpr int NCH = 4;            // o-chunks per block
constexpr int CHO = OC / NCH;     // 32 o per chunk
constexpr int CHR = CHO * KS;     // 288 rows per chunk
constexpr int MT_CH = CHR / 16;   // 18 M-tiles per chunk
constexpr int CTS = 289;          // C^T row stride in words (odd -> conflict-free)
constexpr int WPN = 2 * MTG * 2 * 64 * 8;  // 147456 ushorts in Wprep
// smem layout: mT_hi [0,8192), mT_lo [8192,16384)  (dead after B-frag load)
//              CT f32 [64][289]  bytes [0, 73984)   (aliases mT)
//              so f32 [4][224]   bytes [73984, 77568)
constexpr int SMEM_BYTES = 64 * CTS * 4 + 4 * CHO * TO * 4;  // 77568

__device__ __forceinline__ ushort_t f2bf(float v) {
    uint_t u = __float_as_uint(v);
    return (ushort_t)((u + 0x7fffu + ((u >> 16) & 1u)) >> 16);   // RTNE
}
__device__ __forceinline__ float bf2f(ushort_t h) {
    return __uint_as_float(((uint_t)h) << 16);
}

// Pre-kernel: W[ok][l] f32 -> fragment-ready hi/lo bf16.
// Layout (ushort index): sp*73728 + mt*1024 + ks*512 + lane*8 + i
//   row ok = mt*16 + (lane&15);  k-col l = (lane>>4)*8 + i + 32*ks  (0 if l>=34)
__global__ void wprep_kernel(const float* __restrict__ W, ushort_t* __restrict__ wp) {
    int x = blockIdx.x * 256 + threadIdx.x;
    if (x >= WPN) return;
    int i  = x & 7;
    int ln = (x >> 3) & 63;
    int ks = (x >> 9) & 1;
    int mt = (x >> 10) % MTG;
    int sp = x / (MTG * 1024);
    int ok = mt * 16 + (ln & 15);
    int l  = (ln >> 4) * 8 + i + 32 * ks;
    float v = (l < L) ? W[ok * L + l] : 0.0f;
    ushort_t hi = f2bf(v);
    if (sp == 0) wp[x] = hi;
    else         wp[x] = f2bf(v - bf2f(hi));
}

// Main kernel: one block per batch n. 4 waves.
// Stage 1: MFMA 16x16x32 bf16, 3-product hi/lo split -> relu -> C^T in LDS.
// Stage 2: f32 VALU, lane = d, partial butterfly, epilogue + bias.
// launch_bounds (256,2): LDS already limits to 2 blocks/CU; cap VGPR<=256 to match.
__global__ __launch_bounds__(256, 2) void iconv_mfma(
    const float* __restrict__ pep,
    const float* __restrict__ mhc,
    const ushort_t* __restrict__ wp,
    const float* __restrict__ bias,
    float* __restrict__ out)
{
    __shared__ __align__(16) char smem[SMEM_BYTES];
    const int n    = blockIdx.x;
    const int tid  = threadIdx.x;
    const int lane = tid & 63;
    const int w    = tid >> 6;

    // peptide column (lane = d), kept in registers through both stages
    float p[PEP];
    {
        const float* pp = pep + (size_t)n * PEP * D + lane;
        #pragma unroll
        for (int j = 0; j < PEP; ++j) p[j] = pp[j * D];
    }

    // Stage m^T into LDS as hi/lo bf16, XOR-swizzled: byte = (d*128 + l*2) ^ ((d&7)<<4)
    {
        const float* mp = mhc + (size_t)n * L * D + lane;
        #pragma unroll
        for (int j = 0; j < 16; ++j) {
            int l = w + 4 * j;                       // 0..63 across waves
            float v = (l < L) ? mp[l * D] : 0.0f;
            ushort_t hi = f2bf(v);
            ushort_t lo = f2bf(v - bf2f(hi));
            int byte = (lane * 128 + l * 2) ^ ((lane & 7) << 4);
            *(ushort_t*)(smem + byte)        = hi;
            *(ushort_t*)(smem + 8192 + byte) = lo;
        }
    }
    __syncthreads();

    // B-fragments (m), shared by all chunks: [nt][ks][hi/lo]
    bf16x8 bf[4][2][2];
    #pragma unroll
    for (int nt = 0; nt < 4; ++nt) {
        int d = (lane & 15) + 16 * nt;
        #pragma unroll
        for (int ks = 0; ks < 2; ++ks) {
            int l0 = (lane >> 4) * 8 + 32 * ks;
            int byte = (d * 128 + l0 * 2) ^ ((d & 7) << 4);
            bf[nt][ks][0] = *(const bf16x8*)(smem + byte);
            bf[nt][ks][1] = *(const bf16x8*)(smem + 8192 + byte);
        }
    }
    __syncthreads();   // mT now dead; CT may overwrite its bytes

    float* CT = (float*)smem;                       // [d][CTS]
    float* so = (float*)(smem + 64 * CTS * 4);      // [4][CHO*TO]
    float* CTl = CT + lane * CTS;                   // stage-2 row base (hoisted)

    for (int c = 0; c < NCH; ++c) {
        // ---------- stage 1: MFMA ----------
        f32x4 acc[5][4];
        #pragma unroll
        for (int i = 0; i < 5; ++i)
            #pragma unroll
            for (int nt = 0; nt < 4; ++nt) acc[i][nt] = (f32x4){0.f, 0.f, 0.f, 0.f};

        const ushort_t* wbase = wp + (size_t)(c * MT_CH) * 1024 + lane * 8;
        #pragma unroll
        for (int i = 0; i < 5; ++i) {
            int mtl = w + 4 * i;                    // wave-interleaved M-tiles
            if (mtl < MT_CH) {
                const ushort_t* base = wbase + mtl * 1024;
                bf16x8 ah0 = *(const bf16x8*)(base);
                bf16x8 ah1 = *(const bf16x8*)(base + 512);
                bf16x8 al0 = *(const bf16x8*)(base + MTG * 1024);
                bf16x8 al1 = *(const bf16x8*)(base + MTG * 1024 + 512);
                #pragma unroll
                for (int nt = 0; nt < 4; ++nt) {
                    acc[i][nt] = __builtin_amdgcn_mfma_f32_16x16x32_bf16(ah0, bf[nt][0][0], acc[i][nt], 0, 0, 0);
                    acc[i][nt] = __builtin_amdgcn_mfma_f32_16x16x32_bf16(ah1, bf[nt][1][0], acc[i][nt], 0, 0, 0);
                    acc[i][nt] = __builtin_amdgcn_mfma_f32_16x16x32_bf16(ah0, bf[nt][0][1], acc[i][nt], 0, 0, 0);
                    acc[i][nt] = __builtin_amdgcn_mfma_f32_16x16x32_bf16(ah1, bf[nt][1][1], acc[i][nt], 0, 0, 0);
                    acc[i][nt] = __builtin_amdgcn_mfma_f32_16x16x32_bf16(al0, bf[nt][0][0], acc[i][nt], 0, 0, 0);
                    acc[i][nt] = __builtin_amdgcn_mfma_f32_16x16x32_bf16(al1, bf[nt][1][0], acc[i][nt], 0, 0, 0);
                }
            }
        }

        // relu + write C^T[d][row_local]  (4 consecutive rows per lane per tile)
        #pragma unroll
        for (int i = 0; i < 5; ++i) {
            int mtl = w + 4 * i;
            if (mtl < MT_CH) {
                int r0 = mtl * 16 + (lane >> 4) * 4;
                #pragma unroll
                for (int nt = 0; nt < 4; ++nt) {
                    int d = (lane & 15) + 16 * nt;
                    float* dst = CT + d * CTS + r0;
                    dst[0] = fmaxf(acc[i][nt][0], 0.f);
                    dst[1] = fmaxf(acc[i][nt][1], 0.f);
                    dst[2] = fmaxf(acc[i][nt][2], 0.f);
                    dst[3] = fmaxf(acc[i][nt][3], 0.f);
                }
            }
        }
        __syncthreads();

        // ---------- stage 2: f32 VALU, lane = d ----------
        float a2[8][TO];
        #pragma unroll
        for (int oi = 0; oi < 8; ++oi)
            #pragma unroll
            for (int t = 0; t < TO; ++t) a2[oi][t] = 0.f;

        #pragma unroll
        for (int oi = 0; oi < 8; ++oi) {
            const float* row = CTl + (w * 8 + oi) * KS;   // chunk-local row
            #pragma unroll
            for (int k = 0; k < KS; ++k) {
                float kk = row[k];                        // conflict-free (stride odd)
                #pragma unroll
                for (int t = 0; t < TO; ++t) a2[oi][t] = fmaf(kk, p[t + k], a2[oi][t]);
            }
        }

        // partial butterfly (strides 1,2,4,8); lanes {0,16,32,48} stash 4 partials
        #pragma unroll
        for (int oi = 0; oi < 8; ++oi) {
            #pragma unroll
            for (int t = 0; t < TO; ++t) {
                float a = a2[oi][t];
                a += __shfl_xor(a, 1, 64);
                a += __shfl_xor(a, 2, 64);
                a += __shfl_xor(a, 4, 64);
                a += __shfl_xor(a, 8, 64);
                if ((lane & 15) == 0) so[(lane >> 4) * (CHO * TO) + (w * 8 + oi) * TO + t] = a;
            }
        }
        __syncthreads();

        // epilogue: 224 outputs of this chunk (contiguous in out)
        if (tid < CHO * TO) {
            int o = c * CHO + tid / TO;
            float v = (so[tid] + so[CHO * TO + tid]) +
                      (so[2 * CHO * TO + tid] + so[3 * CHO * TO + tid]);
            out[(size_t)n * OC * TO + c * CHO * TO + tid] = v + bias[o];
        }
        __syncthreads();   // before next chunk overwrites CT/so
    }
}

// ---------------- fallback (f32 VALU, known-good) ----------------
__global__ __launch_bounds__(256, 4) void iconv_f32(
    const float* __restrict__ pep, const float* __restrict__ mhc,
    const float* __restrict__ wsrc, const float* __restrict__ bias,
    float* __restrict__ out)
{
    __shared__ float so[4 * 900];
    const int n = blockIdx.x, tid = threadIdx.x, lane = tid & 63;
    const int w = __builtin_amdgcn_readfirstlane(tid >> 6);
    float m[L];
    { const float* mp = mhc + (size_t)n * L * D + lane;
      #pragma unroll
      for (int l = 0; l < L; ++l) m[l] = mp[l * D]; }
    float p[PEP];
    { const float* pp = pep + (size_t)n * PEP * D + lane;
      #pragma unroll
      for (int j = 0; j < PEP; ++j) p[j] = pp[j * D]; }
    for (int oo = 0; oo < OC / 4; ++oo) {
        const int o = w * (OC / 4) + oo;
        float acc[TO];
        #pragma unroll
        for (int t = 0; t < TO; ++t) acc[t] = 0.f;
        #pragma unroll
        for (int k = 0; k < KS; ++k) {
            const float2* wrow = reinterpret_cast<const float2*>(wsrc + (size_t)o * KS * L);
            float wr[L];
            #pragma unroll
            for (int q = 0; q < L / 2; ++q) {
                float2 v = wrow[k * (L / 2) + q];
                wr[q * 2] = v.x; wr[q * 2 + 1] = v.y;
            }
            float k0 = 0.f, k1 = 0.f, k2 = 0.f, k3 = 0.f;
            #pragma unroll
            for (int l = 0; l < 32; l += 4) {
                k0 = fmaf(m[l], wr[l], k0);   k1 = fmaf(m[l + 1], wr[l + 1], k1);
                k2 = fmaf(m[l + 2], wr[l + 2], k2); k3 = fmaf(m[l + 3], wr[l + 3], k3);
            }
            k0 = fmaf(m[32], wr[32], k0); k1 = fmaf(m[33], wr[33], k1);
            float kk = fmaxf((k0 + k2) + (k1 + k3), 0.f);
            #pragma unroll
            for (int t = 0; t < TO; ++t) acc[t] = fmaf(p[t + k], kk, acc[t]);
        }
        #pragma unroll
        for (int t = 0; t < TO; ++t) {
            float a = acc[t];
            a += __shfl_xor(a, 1, 64); a += __shfl_xor(a, 2, 64);
            a += __shfl_xor(a, 4, 64); a += __shfl_xor(a, 8, 64);
            if ((lane & 15) == 0) so[(lane >> 4) * 900 + o * TO + t] = a;
        }
    }
    __syncthreads();
    float* on = out + (size_t)n * OC * TO;
    for (int i = tid; i < OC * TO; i += 256) {
        int o = i / TO;
        on[i] = (so[i] + so[900 + i]) + (so[1800 + i] + so[2700 + i]) + bias[o];
    }
}

extern "C" void kernel_launch(void* const* d_in, const int* in_sizes, int n_in,
                              void* d_out, int out_size, void* d_ws, size_t ws_size,
                              hipStream_t stream) {
    const float* pep  = (const float*)d_in[0];
    const float* mhc  = (const float*)d_in[1];
    const float* W    = (const float*)d_in[2];
    const float* bias = (const float*)d_in[3];
    float* out        = (float*)d_out;
    const int bs = in_sizes[0] / (PEP * D);

    const size_t need = (size_t)WPN * sizeof(ushort_t);   // 294912 B
    if (d_ws != nullptr && ws_size >= need) {
        ushort_t* wpx = (ushort_t*)d_ws;
        wprep_kernel<<<(WPN + 255) / 256, 256, 0, stream>>>(W, wpx);
        iconv_mfma<<<bs, 256, 0, stream>>>(pep, mhc, wpx, bias, out);
    } else {
        iconv_f32<<<bs, 256, 0, stream>>>(pep, mhc, W, bias, out);
    }
}

// Round 6
// 239.815 us; speedup vs baseline: 1.1932x; 1.1695x over previous
//
#include <hip/hip_runtime.h>

typedef __attribute__((ext_vector_type(8))) short bf16x8;
typedef __attribute__((ext_vector_type(4))) float f32x4;
typedef unsigned short ushort_t;
typedef unsigned int uint_t;

constexpr int PEP = 15;   // peptide length
constexpr int D   = 64;   // feature dim
constexpr int L   = 34;   // mhc length (stage-1 contraction)
constexpr int OC  = 128;  // output channels
constexpr int KS  = 9;    // kernel size
constexpr int TO  = 7;    // output positions
constexpr int OK  = OC * KS;      // 1152 stage-1 rows
constexpr int MTG = OK / 16;      // 72 global M-tiles
constexpr int NCH = 8;            // o-chunks per block
constexpr int CHO = OC / NCH;     // 16 o per chunk
constexpr int CHR = CHO * KS;     // 144 rows per chunk
constexpr int MT_CH = CHR / 16;   // 9 M-tiles per chunk
constexpr int CTS = 145;          // C^T row stride (145%32=17, odd -> reads 2/bank free)
constexpr int SOS = CHO * TO;     // 112 (%32=16 -> writer lanes {0,16,32,48} 2-way free)
constexpr int WPN = 2 * MTG * 2 * 64 * 8;  // 147456 ushorts in Wprep
// smem: CT f32 [64][145]  bytes [0, 37120)   (aliases mT hi/lo staging, 16384 B)
//       so f32 [4][112]   bytes [37120, 38912)
constexpr int SMEM_BYTES = 64 * CTS * 4 + 4 * SOS * 4;  // 38912

__device__ __forceinline__ ushort_t f2bf(float v) {
    uint_t u = __float_as_uint(v);
    return (ushort_t)((u + 0x7fffu + ((u >> 16) & 1u)) >> 16);   // RTNE
}
__device__ __forceinline__ float bf2f(ushort_t h) {
    return __uint_as_float(((uint_t)h) << 16);
}

// Pre-kernel: W[ok][l] f32 -> fragment-ready hi/lo bf16 (unchanged layout).
// ushort index: sp*73728 + mt*1024 + ks*512 + lane*8 + i
//   row ok = mt*16 + (lane&15);  k-col l = (lane>>4)*8 + i + 32*ks  (0 if l>=34)
__global__ void wprep_kernel(const float* __restrict__ W, ushort_t* __restrict__ wp) {
    int x = blockIdx.x * 256 + threadIdx.x;
    if (x >= WPN) return;
    int i  = x & 7;
    int ln = (x >> 3) & 63;
    int ks = (x >> 9) & 1;
    int mt = (x >> 10) % MTG;
    int sp = x / (MTG * 1024);
    int ok = mt * 16 + (ln & 15);
    int l  = (ln >> 4) * 8 + i + 32 * ks;
    float v = (l < L) ? W[ok * L + l] : 0.0f;
    ushort_t hi = f2bf(v);
    if (sp == 0) wp[x] = hi;
    else         wp[x] = f2bf(v - bf2f(hi));
}

// One block per batch n. 4 waves. 8 chunks of 16 o-channels.
// Per chunk: stage-1 MFMA (per-tile pipeline) -> CT; BAR1; stage-2 VALU +
// butterfly -> so; BAR2; epilogue (reads so) runs concurrently with next
// chunk's stage-1 CT writes (disjoint LDS regions; next so-write is after
// next BAR1, so no so WAR hazard).
__global__ __launch_bounds__(256, 3) void iconv_mfma(
    const float* __restrict__ pep,
    const float* __restrict__ mhc,
    const ushort_t* __restrict__ wp,
    const float* __restrict__ bias,
    float* __restrict__ out)
{
    __shared__ __align__(16) char smem[SMEM_BYTES];
    const int n    = blockIdx.x;
    const int tid  = threadIdx.x;
    const int lane = tid & 63;
    const int w    = tid >> 6;

    // peptide column (lane = d), kept in registers through both stages
    float p[PEP];
    {
        const float* pp = pep + (size_t)n * PEP * D + lane;
        #pragma unroll
        for (int j = 0; j < PEP; ++j) p[j] = pp[j * D];
    }

    // Stage m^T into LDS as hi/lo bf16, XOR-swizzled (one-time)
    {
        const float* mp = mhc + (size_t)n * L * D + lane;
        #pragma unroll
        for (int j = 0; j < 16; ++j) {
            int l = w + 4 * j;
            float v = (l < L) ? mp[l * D] : 0.0f;
            ushort_t hi = f2bf(v);
            ushort_t lo = f2bf(v - bf2f(hi));
            int byte = (lane * 128 + l * 2) ^ ((lane & 7) << 4);
            *(ushort_t*)(smem + byte)        = hi;
            *(ushort_t*)(smem + 8192 + byte) = lo;
        }
    }
    __syncthreads();

    // B-fragments (m), persistent in registers: [nt][ks][hi/lo]
    bf16x8 bf[4][2][2];
    #pragma unroll
    for (int nt = 0; nt < 4; ++nt) {
        int d = (lane & 15) + 16 * nt;
        #pragma unroll
        for (int ks = 0; ks < 2; ++ks) {
            int l0 = (lane >> 4) * 8 + 32 * ks;
            int byte = (d * 128 + l0 * 2) ^ ((d & 7) << 4);
            bf[nt][ks][0] = *(const bf16x8*)(smem + byte);
            bf[nt][ks][1] = *(const bf16x8*)(smem + 8192 + byte);
        }
    }
    __syncthreads();   // mT dead; CT may overwrite

    float* CT  = (float*)smem;                      // [d][CTS]
    float* so  = (float*)(smem + 64 * CTS * 4);     // [4][SOS]
    float* CTl = CT + lane * CTS;                   // stage-2 row base

    for (int c = 0; c < NCH; ++c) {
        // ---------- stage 1: MFMA, one M-tile at a time ----------
        #pragma unroll
        for (int i = 0; i < 3; ++i) {
            int mtl = w + 4 * i;                    // tiles w, w+4, w+8
            if (mtl < MT_CH) {
                const ushort_t* base = wp + (size_t)(c * MT_CH + mtl) * 1024 + lane * 8;
                bf16x8 ah0 = *(const bf16x8*)(base);
                bf16x8 ah1 = *(const bf16x8*)(base + 512);
                bf16x8 al0 = *(const bf16x8*)(base + MTG * 1024);
                bf16x8 al1 = *(const bf16x8*)(base + MTG * 1024 + 512);

                f32x4 acc[4];
                #pragma unroll
                for (int nt = 0; nt < 4; ++nt) acc[nt] = (f32x4){0.f, 0.f, 0.f, 0.f};
                #pragma unroll
                for (int nt = 0; nt < 4; ++nt) {
                    acc[nt] = __builtin_amdgcn_mfma_f32_16x16x32_bf16(ah0, bf[nt][0][0], acc[nt], 0, 0, 0);
                    acc[nt] = __builtin_amdgcn_mfma_f32_16x16x32_bf16(ah1, bf[nt][1][0], acc[nt], 0, 0, 0);
                    acc[nt] = __builtin_amdgcn_mfma_f32_16x16x32_bf16(ah0, bf[nt][0][1], acc[nt], 0, 0, 0);
                    acc[nt] = __builtin_amdgcn_mfma_f32_16x16x32_bf16(ah1, bf[nt][1][1], acc[nt], 0, 0, 0);
                    acc[nt] = __builtin_amdgcn_mfma_f32_16x16x32_bf16(al0, bf[nt][0][0], acc[nt], 0, 0, 0);
                    acc[nt] = __builtin_amdgcn_mfma_f32_16x16x32_bf16(al1, bf[nt][1][0], acc[nt], 0, 0, 0);
                }

                int r0 = mtl * 16 + (lane >> 4) * 4;
                #pragma unroll
                for (int nt = 0; nt < 4; ++nt) {
                    int d = (lane & 15) + 16 * nt;
                    float* dst = CT + d * CTS + r0;
                    dst[0] = fmaxf(acc[nt][0], 0.f);
                    dst[1] = fmaxf(acc[nt][1], 0.f);
                    dst[2] = fmaxf(acc[nt][2], 0.f);
                    dst[3] = fmaxf(acc[nt][3], 0.f);
                }
            }
        }
        __syncthreads();   // BAR1: CT complete (cross-wave rows)

        // ---------- stage 2: f32 VALU, lane = d ----------
        float a2[4][TO];
        #pragma unroll
        for (int oi = 0; oi < 4; ++oi)
            #pragma unroll
            for (int t = 0; t < TO; ++t) a2[oi][t] = 0.f;

        #pragma unroll
        for (int oi = 0; oi < 4; ++oi) {
            const float* row = CTl + (w * 4 + oi) * KS;   // conflict-free reads
            #pragma unroll
            for (int k = 0; k < KS; ++k) {
                float kk = row[k];
                #pragma unroll
                for (int t = 0; t < TO; ++t) a2[oi][t] = fmaf(kk, p[t + k], a2[oi][t]);
            }
        }

        // partial butterfly (strides 1,2,4,8); lanes {0,16,32,48} stash partials
        #pragma unroll
        for (int oi = 0; oi < 4; ++oi) {
            #pragma unroll
            for (int t = 0; t < TO; ++t) {
                float a = a2[oi][t];
                a += __shfl_xor(a, 1, 64);
                a += __shfl_xor(a, 2, 64);
                a += __shfl_xor(a, 4, 64);
                a += __shfl_xor(a, 8, 64);
                if ((lane & 15) == 0) so[(lane >> 4) * SOS + (w * 4 + oi) * TO + t] = a;
            }
        }
        __syncthreads();   // BAR2: so complete; CT reads complete

        // epilogue: this chunk's 112 outputs (contiguous in out)
        if (tid < SOS) {
            int o = c * CHO + tid / TO;
            float v = (so[tid] + so[SOS + tid]) +
                      (so[2 * SOS + tid] + so[3 * SOS + tid]);
            out[(size_t)n * OC * TO + c * SOS + tid] = v + bias[o];
        }
        // no barrier: next stage-1 writes CT only (so disjoint); next so-write
        // is after next BAR1 which orders it against these so-reads.
    }
}

// ---------------- fallback (f32 VALU, known-good) ----------------
__global__ __launch_bounds__(256, 4) void iconv_f32(
    const float* __restrict__ pep, const float* __restrict__ mhc,
    const float* __restrict__ wsrc, const float* __restrict__ bias,
    float* __restrict__ out)
{
    __shared__ float so[4 * 900];
    const int n = blockIdx.x, tid = threadIdx.x, lane = tid & 63;
    const int w = __builtin_amdgcn_readfirstlane(tid >> 6);
    float m[L];
    { const float* mp = mhc + (size_t)n * L * D + lane;
      #pragma unroll
      for (int l = 0; l < L; ++l) m[l] = mp[l * D]; }
    float p[PEP];
    { const float* pp = pep + (size_t)n * PEP * D + lane;
      #pragma unroll
      for (int j = 0; j < PEP; ++j) p[j] = pp[j * D]; }
    for (int oo = 0; oo < OC / 4; ++oo) {
        const int o = w * (OC / 4) + oo;
        float acc[TO];
        #pragma unroll
        for (int t = 0; t < TO; ++t) acc[t] = 0.f;
        #pragma unroll
        for (int k = 0; k < KS; ++k) {
            const float2* wrow = reinterpret_cast<const float2*>(wsrc + (size_t)o * KS * L);
            float wr[L];
            #pragma unroll
            for (int q = 0; q < L / 2; ++q) {
                float2 v = wrow[k * (L / 2) + q];
                wr[q * 2] = v.x; wr[q * 2 + 1] = v.y;
            }
            float k0 = 0.f, k1 = 0.f, k2 = 0.f, k3 = 0.f;
            #pragma unroll
            for (int l = 0; l < 32; l += 4) {
                k0 = fmaf(m[l], wr[l], k0);   k1 = fmaf(m[l + 1], wr[l + 1], k1);
                k2 = fmaf(m[l + 2], wr[l + 2], k2); k3 = fmaf(m[l + 3], wr[l + 3], k3);
            }
            k0 = fmaf(m[32], wr[32], k0); k1 = fmaf(m[33], wr[33], k1);
            float kk = fmaxf((k0 + k2) + (k1 + k3), 0.f);
            #pragma unroll
            for (int t = 0; t < TO; ++t) acc[t] = fmaf(p[t + k], kk, acc[t]);
        }
        #pragma unroll
        for (int t = 0; t < TO; ++t) {
            float a = acc[t];
            a += __shfl_xor(a, 1, 64); a += __shfl_xor(a, 2, 64);
            a += __shfl_xor(a, 4, 64); a += __shfl_xor(a, 8, 64);
            if ((lane & 15) == 0) so[(lane >> 4) * 900 + o * TO + t] = a;
        }
    }
    __syncthreads();
    float* on = out + (size_t)n * OC * TO;
    for (int i = tid; i < OC * TO; i += 256) {
        int o = i / TO;
        on[i] = (so[i] + so[900 + i]) + (so[1800 + i] + so[2700 + i]) + bias[o];
    }
}

extern "C" void kernel_launch(void* const* d_in, const int* in_sizes, int n_in,
                              void* d_out, int out_size, void* d_ws, size_t ws_size,
                              hipStream_t stream) {
    const float* pep  = (const float*)d_in[0];
    const float* mhc  = (const float*)d_in[1];
    const float* W    = (const float*)d_in[2];
    const float* bias = (const float*)d_in[3];
    float* out        = (float*)d_out;
    const int bs = in_sizes[0] / (PEP * D);

    const size_t need = (size_t)WPN * sizeof(ushort_t);   // 294912 B
    if (d_ws != nullptr && ws_size >= need) {
        ushort_t* wpx = (ushort_t*)d_ws;
        wprep_kernel<<<(WPN + 255) / 256, 256, 0, stream>>>(W, wpx);
        iconv_mfma<<<bs, 256, 0, stream>>>(pep, mhc, wpx, bias, out);
    } else {
        iconv_f32<<<bs, 256, 0, stream>>>(pep, mhc, W, bias, out);
    }
}

// Round 7
// 166.586 us; speedup vs baseline: 1.7177x; 1.4396x over previous
//
#include <hip/hip_runtime.h>

typedef __attribute__((ext_vector_type(8))) short bf16x8;
typedef __attribute__((ext_vector_type(4))) float f32x4;
typedef unsigned short ushort_t;
typedef unsigned int uint_t;

constexpr int PEP = 15;   // peptide length
constexpr int D   = 64;   // feature dim
constexpr int L   = 34;   // mhc length (stage-1 contraction)
constexpr int OC  = 128;  // output channels
constexpr int KS  = 9;    // kernel size
constexpr int TO  = 7;    // output positions
constexpr int OK  = OC * KS;      // 1152 stage-1 rows
constexpr int MTG = OK / 16;      // 72 global M-tiles
constexpr int NCH = 8;            // o-chunks total per n
constexpr int NCHB = 4;           // chunks per block (grid-split 2x)
constexpr int CHO = OC / NCH;     // 16 o per chunk
constexpr int MT_CH = (CHO * KS) / 16;  // 9 M-tiles per chunk
constexpr int CTS = 145;          // C^T row stride (odd -> stage-2 reads 2/bank free)
constexpr int SOS = CHO * TO;     // 112 (%32=16 -> writer lanes {15,31,47,63} 2-way free)
constexpr int WPN = 2 * MTG * 2 * 64 * 8;  // 147456 ushorts in Wprep
// smem: CT f32 [64][145] bytes [0,37120) (aliases one-time mT staging, 16384 B)
//       so f32 [4][112]  bytes [37120, 38912)
constexpr int SMEM_BYTES = 64 * CTS * 4 + 4 * SOS * 4;  // 38912

__device__ __forceinline__ ushort_t f2bf(float v) {
    uint_t u = __float_as_uint(v);
    return (ushort_t)((u + 0x7fffu + ((u >> 16) & 1u)) >> 16);   // RTNE
}
__device__ __forceinline__ float bf2f(ushort_t h) {
    return __uint_as_float(((uint_t)h) << 16);
}

// DPP row_shr:N accumulate (pure VALU — no LDS-pipe traffic, unlike __shfl_xor
// which lowers to ds_bpermute). bound_ctrl=true zero-fills lanes < N in row.
template <int CTRL>
__device__ __forceinline__ float dpp_shr_add(float v) {
    int x = __builtin_amdgcn_update_dpp(0, __float_as_int(v), CTRL, 0xF, 0xF, true);
    return v + __int_as_float(x);
}

// Pre-kernel: W[ok][l] f32 -> fragment-ready hi/lo bf16 (unchanged layout).
// ushort index: sp*73728 + mt*1024 + ks*512 + lane*8 + i
//   row ok = mt*16 + (lane&15);  k-col l = (lane>>4)*8 + i + 32*ks  (0 if l>=34)
__global__ void wprep_kernel(const float* __restrict__ W, ushort_t* __restrict__ wp) {
    int x = blockIdx.x * 256 + threadIdx.x;
    if (x >= WPN) return;
    int i  = x & 7;
    int ln = (x >> 3) & 63;
    int ks = (x >> 9) & 1;
    int mt = (x >> 10) % MTG;
    int sp = x / (MTG * 1024);
    int ok = mt * 16 + (ln & 15);
    int l  = (ln >> 4) * 8 + i + 32 * ks;
    float v = (l < L) ? W[ok * L + l] : 0.0f;
    ushort_t hi = f2bf(v);
    if (sp == 0) wp[x] = hi;
    else         wp[x] = f2bf(v - bf2f(hi));
}

// Grid (bs, 2): block = (n, half). Each block: 4 chunks of 16 o-channels.
// Per chunk: stage-1 MFMA -> CT; BAR1; stage-2 VALU + DPP row-reduce -> so
// (4 partials); BAR2; epilogue. The 9th M-tile rotates across waves by chunk
// to remove the BAR1 straggler.
__global__ __launch_bounds__(256, 4) void iconv_mfma(
    const float* __restrict__ pep,
    const float* __restrict__ mhc,
    const ushort_t* __restrict__ wp,
    const float* __restrict__ bias,
    float* __restrict__ out)
{
    __shared__ __align__(16) char smem[SMEM_BYTES];
    const int n    = blockIdx.x;
    const int c0   = blockIdx.y * NCHB;             // chunk offset for this block
    const int tid  = threadIdx.x;
    const int lane = tid & 63;
    const int w    = tid >> 6;

    // peptide column (lane = d), kept in registers through both stages
    float p[PEP];
    {
        const float* pp = pep + (size_t)n * PEP * D + lane;
        #pragma unroll
        for (int j = 0; j < PEP; ++j) p[j] = pp[j * D];
    }

    // Stage m^T into LDS as hi/lo bf16, XOR-swizzled (one-time)
    {
        const float* mp = mhc + (size_t)n * L * D + lane;
        #pragma unroll
        for (int j = 0; j < 16; ++j) {
            int l = w + 4 * j;
            float v = (l < L) ? mp[l * D] : 0.0f;
            ushort_t hi = f2bf(v);
            ushort_t lo = f2bf(v - bf2f(hi));
            int byte = (lane * 128 + l * 2) ^ ((lane & 7) << 4);
            *(ushort_t*)(smem + byte)        = hi;
            *(ushort_t*)(smem + 8192 + byte) = lo;
        }
    }
    __syncthreads();

    // B-fragments (m), persistent in registers: [nt][ks][hi/lo]
    bf16x8 bf[4][2][2];
    #pragma unroll
    for (int nt = 0; nt < 4; ++nt) {
        int d = (lane & 15) + 16 * nt;
        #pragma unroll
        for (int ks = 0; ks < 2; ++ks) {
            int l0 = (lane >> 4) * 8 + 32 * ks;
            int byte = (d * 128 + l0 * 2) ^ ((d & 7) << 4);
            bf[nt][ks][0] = *(const bf16x8*)(smem + byte);
            bf[nt][ks][1] = *(const bf16x8*)(smem + 8192 + byte);
        }
    }
    __syncthreads();   // mT dead; CT may overwrite

    float* CT  = (float*)smem;                      // [d][CTS]
    float* so  = (float*)(smem + 64 * CTS * 4);     // [4][SOS]
    float* CTl = CT + lane * CTS;                   // stage-2 row base

    // one M-tile of stage 1: load W-frags, 6 MFMAs (hi/lo 3-product), relu->CT
    auto do_tile = [&](int cg, int mtl) {
        const ushort_t* base = wp + (size_t)(cg * MT_CH + mtl) * 1024 + lane * 8;
        bf16x8 ah0 = *(const bf16x8*)(base);
        bf16x8 ah1 = *(const bf16x8*)(base + 512);
        bf16x8 al0 = *(const bf16x8*)(base + MTG * 1024);
        bf16x8 al1 = *(const bf16x8*)(base + MTG * 1024 + 512);

        f32x4 acc[4];
        #pragma unroll
        for (int nt = 0; nt < 4; ++nt) acc[nt] = (f32x4){0.f, 0.f, 0.f, 0.f};
        #pragma unroll
        for (int nt = 0; nt < 4; ++nt) {
            acc[nt] = __builtin_amdgcn_mfma_f32_16x16x32_bf16(ah0, bf[nt][0][0], acc[nt], 0, 0, 0);
            acc[nt] = __builtin_amdgcn_mfma_f32_16x16x32_bf16(ah1, bf[nt][1][0], acc[nt], 0, 0, 0);
            acc[nt] = __builtin_amdgcn_mfma_f32_16x16x32_bf16(ah0, bf[nt][0][1], acc[nt], 0, 0, 0);
            acc[nt] = __builtin_amdgcn_mfma_f32_16x16x32_bf16(ah1, bf[nt][1][1], acc[nt], 0, 0, 0);
            acc[nt] = __builtin_amdgcn_mfma_f32_16x16x32_bf16(al0, bf[nt][0][0], acc[nt], 0, 0, 0);
            acc[nt] = __builtin_amdgcn_mfma_f32_16x16x32_bf16(al1, bf[nt][1][0], acc[nt], 0, 0, 0);
        }

        int r0 = mtl * 16 + (lane >> 4) * 4;
        #pragma unroll
        for (int nt = 0; nt < 4; ++nt) {
            int d = (lane & 15) + 16 * nt;
            float* dst = CT + d * CTS + r0;
            dst[0] = fmaxf(acc[nt][0], 0.f);
            dst[1] = fmaxf(acc[nt][1], 0.f);
            dst[2] = fmaxf(acc[nt][2], 0.f);
            dst[3] = fmaxf(acc[nt][3], 0.f);
        }
    };

    for (int c = 0; c < NCHB; ++c) {
        const int cg = c0 + c;                      // global chunk id

        // ---------- stage 1: tiles {w, w+4} + rotated 9th tile ----------
        do_tile(cg, w);
        do_tile(cg, w + 4);
        if (w == (cg & 3)) do_tile(cg, 8);          // balanced across chunks
        __syncthreads();   // BAR1: CT complete

        // ---------- stage 2: f32 VALU, lane = d ----------
        float a2[4][TO];
        #pragma unroll
        for (int oi = 0; oi < 4; ++oi)
            #pragma unroll
            for (int t = 0; t < TO; ++t) a2[oi][t] = 0.f;

        #pragma unroll
        for (int oi = 0; oi < 4; ++oi) {
            const float* row = CTl + (w * 4 + oi) * KS;   // conflict-free reads
            #pragma unroll
            for (int k = 0; k < KS; ++k) {
                float kk = row[k];
                #pragma unroll
                for (int t = 0; t < TO; ++t) a2[oi][t] = fmaf(kk, p[t + k], a2[oi][t]);
            }
        }

        // DPP row-reduce over 16-lane groups (VALU only, no LDS traffic);
        // group sum lands in lane 15 of each row16; 4 partials -> so.
        #pragma unroll
        for (int oi = 0; oi < 4; ++oi) {
            #pragma unroll
            for (int t = 0; t < TO; ++t) {
                float a = a2[oi][t];
                a = dpp_shr_add<0x111>(a);   // row_shr:1
                a = dpp_shr_add<0x112>(a);   // row_shr:2
                a = dpp_shr_add<0x114>(a);   // row_shr:4
                a = dpp_shr_add<0x118>(a);   // row_shr:8
                if ((lane & 15) == 15) so[(lane >> 4) * SOS + (w * 4 + oi) * TO + t] = a;
            }
        }
        __syncthreads();   // BAR2: so complete; CT reads complete

        // epilogue: this chunk's 112 outputs (contiguous in out)
        if (tid < SOS) {
            int o = cg * CHO + tid / TO;
            float v = (so[tid] + so[SOS + tid]) +
                      (so[2 * SOS + tid] + so[3 * SOS + tid]);
            out[(size_t)n * OC * TO + cg * SOS + tid] = v + bias[o];
        }
        // no barrier: next stage-1 writes CT only (so disjoint); next so-write
        // is after next BAR1 which orders it against these so-reads.
    }
}

// ---------------- fallback (f32 VALU, known-good) ----------------
__global__ __launch_bounds__(256, 4) void iconv_f32(
    const float* __restrict__ pep, const float* __restrict__ mhc,
    const float* __restrict__ wsrc, const float* __restrict__ bias,
    float* __restrict__ out)
{
    __shared__ float so[4 * 900];
    const int n = blockIdx.x, tid = threadIdx.x, lane = tid & 63;
    const int w = __builtin_amdgcn_readfirstlane(tid >> 6);
    float m[L];
    { const float* mp = mhc + (size_t)n * L * D + lane;
      #pragma unroll
      for (int l = 0; l < L; ++l) m[l] = mp[l * D]; }
    float p[PEP];
    { const float* pp = pep + (size_t)n * PEP * D + lane;
      #pragma unroll
      for (int j = 0; j < PEP; ++j) p[j] = pp[j * D]; }
    for (int oo = 0; oo < OC / 4; ++oo) {
        const int o = w * (OC / 4) + oo;
        float acc[TO];
        #pragma unroll
        for (int t = 0; t < TO; ++t) acc[t] = 0.f;
        #pragma unroll
        for (int k = 0; k < KS; ++k) {
            const float2* wrow = reinterpret_cast<const float2*>(wsrc + (size_t)o * KS * L);
            float wr[L];
            #pragma unroll
            for (int q = 0; q < L / 2; ++q) {
                float2 v = wrow[k * (L / 2) + q];
                wr[q * 2] = v.x; wr[q * 2 + 1] = v.y;
            }
            float k0 = 0.f, k1 = 0.f, k2 = 0.f, k3 = 0.f;
            #pragma unroll
            for (int l = 0; l < 32; l += 4) {
                k0 = fmaf(m[l], wr[l], k0);   k1 = fmaf(m[l + 1], wr[l + 1], k1);
                k2 = fmaf(m[l + 2], wr[l + 2], k2); k3 = fmaf(m[l + 3], wr[l + 3], k3);
            }
            k0 = fmaf(m[32], wr[32], k0); k1 = fmaf(m[33], wr[33], k1);
            float kk = fmaxf((k0 + k2) + (k1 + k3), 0.f);
            #pragma unroll
            for (int t = 0; t < TO; ++t) acc[t] = fmaf(p[t + k], kk, acc[t]);
        }
        #pragma unroll
        for (int t = 0; t < TO; ++t) {
            float a = acc[t];
            a += __shfl_xor(a, 1, 64); a += __shfl_xor(a, 2, 64);
            a += __shfl_xor(a, 4, 64); a += __shfl_xor(a, 8, 64);
            if ((lane & 15) == 0) so[(lane >> 4) * 900 + o * TO + t] = a;
        }
    }
    __syncthreads();
    float* on = out + (size_t)n * OC * TO;
    for (int i = tid; i < OC * TO; i += 256) {
        int o = i / TO;
        on[i] = (so[i] + so[900 + i]) + (so[1800 + i] + so[2700 + i]) + bias[o];
    }
}

extern "C" void kernel_launch(void* const* d_in, const int* in_sizes, int n_in,
                              void* d_out, int out_size, void* d_ws, size_t ws_size,
                              hipStream_t stream) {
    const float* pep  = (const float*)d_in[0];
    const float* mhc  = (const float*)d_in[1];
    const float* W    = (const float*)d_in[2];
    const float* bias = (const float*)d_in[3];
    float* out        = (float*)d_out;
    const int bs = in_sizes[0] / (PEP * D);

    const size_t need = (size_t)WPN * sizeof(ushort_t);   // 294912 B
    if (d_ws != nullptr && ws_size >= need) {
        ushort_t* wpx = (ushort_t*)d_ws;
        wprep_kernel<<<(WPN + 255) / 256, 256, 0, stream>>>(W, wpx);
        iconv_mfma<<<dim3(bs, 2), 256, 0, stream>>>(pep, mhc, wpx, bias, out);
    } else {
        iconv_f32<<<bs, 256, 0, stream>>>(pep, mhc, W, bias, out);
    }
}